// Round 1
// baseline (429.445 us; speedup 1.0000x reference)
//
#include <hip/hip_runtime.h>
#include <stdint.h>

#define N_BATCH 32
#define CHN     256
#define HW      56
#define HP      58      // padded H/W
#define WORDS   8       // 256 channels / 32 bits
#define HPT     7       // outputs per thread (vertical); 56 = 8*7

// ---------------- weight binarization: wbits[o][tap][8], wpop[o][tap] -------
__global__ __launch_bounds__(256) void binw_kernel(const float* __restrict__ wsrc,
                                                   uint32_t* __restrict__ wbits,
                                                   int* __restrict__ wpop) {
    int idx = blockIdx.x * 256 + threadIdx.x;      // (o*9 + tap)
    if (idx >= 256 * 9) return;
    int o   = idx / 9;
    int tap = idx - o * 9;
    const float* p = wsrc + (size_t)o * 2304 + tap;  // w[o][i][kh][kw], i-stride = 9
    uint32_t wd[WORDS];
#pragma unroll
    for (int k = 0; k < WORDS; k++) wd[k] = 0u;
#pragma unroll 32
    for (int i = 0; i < 256; i++) {
        uint32_t b = p[(size_t)i * 9] > 0.0f ? 1u : 0u;
        wd[i >> 5] |= b << (i & 31);
    }
    int pc = 0;
#pragma unroll
    for (int k = 0; k < WORDS; k++) {
        wbits[(size_t)idx * WORDS + k] = wd[k];
        pc += __builtin_popcount(wd[k]);
    }
    wpop[idx] = pc;
}

// ---------------- x binarization into zero-padded bitplane ------------------
// xpad[n][hp][wp][8], hp/wp in [0,58), border rows/cols are all-zero words.
__global__ __launch_bounds__(64) void binx_kernel(const float* __restrict__ x,
                                                  uint32_t* __restrict__ xpad) {
    int wp = threadIdx.x;          // 0..63, active 0..57
    int hp = blockIdx.x;           // 0..57
    int n  = blockIdx.y;
    if (wp >= HP) return;
    uint32_t wd[WORDS];
#pragma unroll
    for (int k = 0; k < WORDS; k++) wd[k] = 0u;
    int h = hp - 1, w = wp - 1;
    if (h >= 0 && h < HW && w >= 0 && w < HW) {
        const float* xp = x + (size_t)n * CHN * HW * HW + (size_t)h * HW + w;
#pragma unroll 32
        for (int c = 0; c < CHN; c++) {
            uint32_t b = xp[(size_t)c * HW * HW] > 0.0f ? 1u : 0u;
            wd[c >> 5] |= b << (c & 31);
        }
    }
    uint32_t* dst = xpad + ((size_t)(n * HP + hp) * HP + wp) * WORDS;
    uint4 a = make_uint4(wd[0], wd[1], wd[2], wd[3]);
    uint4 bq = make_uint4(wd[4], wd[5], wd[6], wd[7]);
    ((uint4*)dst)[0] = a;
    ((uint4*)dst)[1] = bq;
}

// ---------------- binary conv: XOR + popcount -------------------------------
// grid: (7 strips, 64 o-groups, 32 n), block 256 = 4 waves.
// Wave wv handles o = blockIdx.y*4 + wv; all 4 waves share the same 64-pixel
// base strip (L1 reuse of x bits). Each lane computes HPT=7 vertical outputs.
__global__ __launch_bounds__(256) void conv_kernel(const uint32_t* __restrict__ xpad,
                                                   const uint32_t* __restrict__ wbits,
                                                   const int* __restrict__ wpop,
                                                   float* __restrict__ out) {
    int lane = threadIdx.x & 63;
    int wv   = threadIdx.x >> 6;
    int o    = __builtin_amdgcn_readfirstlane(blockIdx.y * 4 + wv); // force scalar
    int n    = blockIdx.z;
    int b    = blockIdx.x * 64 + lane;   // [0,448): base-pixel index
    int hb_i = b / 56;                   // 0..7
    int w    = b - hb_i * 56;            // 0..55
    int hb   = hb_i * HPT;               // base output row, 0..49

    // weights for this o: 72 u32, wave-uniform -> s_load, SGPR operands
    uint32_t W[72];
    const uint32_t* wb = wbits + (size_t)o * 72;
#pragma unroll
    for (int i = 0; i < 72; i++) W[i] = wb[i];
    int wp9[9];
    const int* wpp = wpop + (size_t)o * 9;
#pragma unroll
    for (int t = 0; t < 9; t++) wp9[t] = wpp[t];

    int acc[HPT];
#pragma unroll
    for (int r = 0; r < HPT; r++) acc[r] = 0;

    // padded row (hb + j) covers unpadded row hb + j - 1; cols w..w+2 padded
    const uint32_t* xbase = xpad + ((size_t)(n * HP + hb) * HP + w) * WORDS;
#pragma unroll
    for (int j = 0; j < HPT + 2; j++) {
        const uint32_t* xr = xbase + (size_t)j * HP * WORDS;
        uint32_t X[24];
#pragma unroll
        for (int i = 0; i < 6; i++) {
            uint4 v = ((const uint4*)xr)[i];
            X[4 * i + 0] = v.x; X[4 * i + 1] = v.y;
            X[4 * i + 2] = v.z; X[4 * i + 3] = v.w;
        }
#pragma unroll
        for (int dh = 0; dh < 3; dh++) {
            int r = j - dh;              // output row index using this x row
            if (r >= 0 && r < HPT) {
#pragma unroll
                for (int dw = 0; dw < 3; dw++) {
#pragma unroll
                    for (int k = 0; k < 8; k++)
                        acc[r] += __builtin_popcount(X[dw * 8 + k] ^ W[(dh * 3 + dw) * 8 + k]);
                }
            }
        }
    }

    float* obase = out + (((size_t)n * 256 + o) * 56 + hb) * 56 + w;
    bool edge_w = (w == 0) | (w == 55);
#pragma unroll
    for (int r = 0; r < HPT; r++) {
        int hh  = hb + r;
        int val = 2304 - 2 * acc[r];
        if (edge_w | (hh == 0) | (hh == 55)) {
            int corr = 0;
#pragma unroll
            for (int dh = -1; dh <= 1; dh++) {
#pragma unroll
                for (int dw = -1; dw <= 1; dw++) {
                    if ((unsigned)(hh + dh) >= 56u || (unsigned)(w + dw) >= 56u)
                        corr += 256 - 2 * wp9[(dh + 1) * 3 + (dw + 1)];
                }
            }
            val -= corr;
        }
        obase[(size_t)r * 56] = (float)val;
    }
}

extern "C" void kernel_launch(void* const* d_in, const int* in_sizes, int n_in,
                              void* d_out, int out_size, void* d_ws, size_t ws_size,
                              hipStream_t stream) {
    const float* x    = (const float*)d_in[0];
    const float* wsrc = (const float*)d_in[1];
    float* out = (float*)d_out;

    uint32_t* xpad = (uint32_t*)d_ws;                       // 32*58*58*8 u32 = 3.44 MB
    size_t xpad_elems = (size_t)N_BATCH * HP * HP * WORDS;
    uint32_t* wbits = xpad + xpad_elems;                    // 18432 u32
    int* wpop = (int*)(wbits + 256 * 9 * WORDS);            // 2304 int

    binw_kernel<<<9, 256, 0, stream>>>(wsrc, wbits, wpop);
    binx_kernel<<<dim3(HP, N_BATCH), 64, 0, stream>>>(x, xpad);
    conv_kernel<<<dim3(7, 64, N_BATCH), 256, 0, stream>>>(xpad, wbits, wpop, out);
}